// Round 7
// baseline (98.063 us; speedup 1.0000x reference)
//
#include <hip/hip_runtime.h>
#include <hip/hip_bf16.h>
#include <cstdint>

// Problem constants
#define Bn 8
#define Cn 64
#define Hn 112
#define Wn 112
#define On 64
#define Ln (Hn * Wn)   // 12544 = 98 * 128
#define HP 114
#define WP 114

typedef __attribute__((ext_vector_type(4)))  float f32x4;
typedef __attribute__((ext_vector_type(16))) float f32x16;
typedef __attribute__((ext_vector_type(8)))  short bf16x8;
typedef __attribute__((ext_vector_type(4)))  unsigned int u32x4;

__device__ __forceinline__ unsigned f2bf(float f) {
    unsigned u = __float_as_uint(f);
    unsigned r = 0x7fffu + ((u >> 16) & 1u);
    return (u + r) >> 16;   // RNE bf16 in low 16 bits
}

// -----------------------------------------------------------------------------
// Kernel 1: weight [O][C][3][3] f32 -> wpk, bf16 in 32x32x16 A-fragment order:
//   frag idx = p*8 + wr*4 + kc ; per lane (of 64):
//     o = wr*32 + (lane&31),  c = kc*16 + (lane>>5)*8 + j   (j = 0..7)
// -----------------------------------------------------------------------------
__global__ __launch_bounds__(64) void wpack_kernel(const float* __restrict__ w,
                                                   unsigned short* __restrict__ wpk) {
    int idx = blockIdx.x;             // [0,72) = p*8 + wr*4 + kc
    int kc = idx & 3, wr = (idx >> 2) & 1, p = idx >> 3;
    int lane = threadIdx.x;
    int o  = wr * 32 + (lane & 31);
    int cb = kc * 16 + (lane >> 5) * 8;
    unsigned pk[4];
#pragma unroll
    for (int j = 0; j < 4; j++) {
        float v0 = w[((size_t)o * Cn + cb + 2 * j) * 9 + p];
        float v1 = w[((size_t)o * Cn + cb + 2 * j + 1) * 9 + p];
        pk[j] = f2bf(v0) | (f2bf(v1) << 16);
    }
    u32x4 v; v[0] = pk[0]; v[1] = pk[1]; v[2] = pk[2]; v[3] = pk[3];
    reinterpret_cast<u32x4*>(wpk)[idx * 64 + lane] = v;
}

// -----------------------------------------------------------------------------
// Kernel 2: FUSED implicit-GEMM conv, 32x32x16 MFMA, per-pixel tap mask.
// WAVE-OWNS-ALL-O: block = 256 thr (4 waves), each wave owns ONE 32-px tile
// and ALL 64 output channels (acc0/acc1 = two 32x32 tiles). This halves LDS
// B-fragment reads vs the 2(O)x4(px) wavegrid: 36 ds_read_b128 now feed
// 72 MFMAs per tile. Block owns 128 consecutive pixels of one image; stages
// 4 padded input rows NCHW f32 -> XOR-swizzled NHWC bf16 LDS (58.4 KB).
// A-fragments (both wr halves, 8 contiguous KB per tap) double-buffered one
// tap ahead from L2-hot wpk. __launch_bounds__(256,2): 2 blocks/CU (117KB
// LDS). XCD pinning: b = blockIdx.x & 7.
// -----------------------------------------------------------------------------
__global__ __launch_bounds__(256, 2) void conv_fused(const float* __restrict__ x,
                                                     const unsigned short* __restrict__ wpk,
                                                     const int* __restrict__ mask_idx,
                                                     float* __restrict__ out) {
    __shared__ char xs[4 * WP * Cn * 2];   // 58368 B, [row][wp][c] bf16, 16B-slot swizzle

    int b  = blockIdx.x & 7;                // image -> XCD pin
    int lt = blockIdx.x >> 3;               // 0..97
    int l0 = lt * 128;
    int oh0 = l0 / Wn;                      // tile spans output rows oh0, oh0+1

    int tid  = threadIdx.x;
    int wave = tid >> 6, lane = tid & 63;   // wave = px-tile 0..3
    int hi = lane >> 5;
    int li = lane & 31;

    int lg = l0 + wave * 32 + li;           // this lane's pixel
    int oh = lg / Wn, ow = lg - oh * Wn;
    int r  = oh - oh0;                      // 0 or 1
    int mv = mask_idx[lg];

    // ---- Staging: NCHW f32 -> swizzled NHWC bf16 LDS (rows oh0-1..oh0+2).
    const float* xb = x + (size_t)b * Cn * Hn * Wn;
#pragma unroll
    for (int it = 0; it < 15; ++it) {
        int q = tid + it * 256;
        if (q < 4 * 8 * WP) {               // 3648 16B chunks
            int row = q / (8 * WP);
            int rem = q - row * (8 * WP);
            int c8  = rem / WP;
            int wp  = rem - c8 * WP;
            int h = oh0 + row - 1;
            int w = wp - 1;
            bool inb = ((unsigned)h < (unsigned)Hn) & ((unsigned)w < (unsigned)Wn);
            const float* s = xb + ((size_t)(c8 * 8) * Hn + (inb ? h : 0)) * Wn + (inb ? w : 0);
            unsigned pk[4];
#pragma unroll
            for (int j = 0; j < 4; ++j) {
                float v0 = s[(size_t)(2 * j)     * (Hn * Wn)];
                float v1 = s[(size_t)(2 * j + 1) * (Hn * Wn)];
                if (!inb) { v0 = 0.f; v1 = 0.f; }
                pk[j] = f2bf(v0) | (f2bf(v1) << 16);
            }
            int qs = (row * WP + wp) * 8 + c8;          // 16B slot index
            int off = (qs * 16) ^ ((wp & 7) << 4);      // write-side swizzle
            u32x4 v; v[0] = pk[0]; v[1] = pk[1]; v[2] = pk[2]; v[3] = pk[3];
            *reinterpret_cast<u32x4*>(xs + off) = v;
        }
    }

    // A-fragment double buffer: 8 frags per tap (wr0 kc0..3, wr1 kc0..3).
    const u32x4* wv = reinterpret_cast<const u32x4*>(wpk);
    u32x4 af0[8], af1[8];
#pragma unroll
    for (int f = 0; f < 8; ++f) af0[f] = wv[f * 64 + lane];   // tap p=0

    f32x16 acc0 = {}, acc1 = {};
    const u32x4 vzero = {0u, 0u, 0u, 0u};

    __syncthreads();

#pragma unroll
    for (int p = 0; p < 9; ++p) {
        // Fully-unrolled loop: (p&1) is compile-time -> static buffer select.
        u32x4* cur = (p & 1) ? af1 : af0;
        u32x4* nxt = (p & 1) ? af0 : af1;
        if (p < 8) {
#pragma unroll
            for (int f = 0; f < 8; ++f)
                nxt[f] = wv[((p + 1) * 8 + f) * 64 + lane];
        }

        int dh = p / 3, dw = p - dh * 3;
        int wq   = ow + dw;
        int base = ((r + dh) * WP + wq) << 7;
        int swz  = (wq & 7) << 4;
        u32x4 bv[4];
#pragma unroll
        for (int kc = 0; kc < 4; ++kc) {
            int off = (base + ((2 * kc + hi) << 4)) ^ swz;
            bv[kc] = *reinterpret_cast<const u32x4*>(xs + off);
        }
        if (mv == p) { bv[0] = vzero; bv[1] = vzero; bv[2] = vzero; bv[3] = vzero; }

#pragma unroll
        for (int kc = 0; kc < 4; ++kc) {
            bf16x8 bb = *reinterpret_cast<bf16x8*>(&bv[kc]);
            bf16x8 a0 = *reinterpret_cast<bf16x8*>(&cur[kc]);
            bf16x8 a1 = *reinterpret_cast<bf16x8*>(&cur[4 + kc]);
            acc0 = __builtin_amdgcn_mfma_f32_32x32x16_bf16(a0, bb, acc0, 0, 0, 0);
            acc1 = __builtin_amdgcn_mfma_f32_32x32x16_bf16(a1, bb, acc1, 0, 0, 0);
        }
    }

    // Epilogue: D col=lane&31 (=pixel), row=(reg&3)+8*(reg>>2)+4*hi (=o).
    float* ob = out + (size_t)(b * On) * Ln + lg;
#pragma unroll
    for (int reg = 0; reg < 16; ++reg) {
        int orow = (reg & 3) + 8 * (reg >> 2) + 4 * hi;
        ob[(size_t)orow * Ln]        = acc0[reg];
        ob[(size_t)(orow + 32) * Ln] = acc1[reg];
    }
}

// -----------------------------------------------------------------------------
extern "C" void kernel_launch(void* const* d_in, const int* in_sizes, int n_in,
                              void* d_out, int out_size, void* d_ws, size_t ws_size,
                              hipStream_t stream) {
    const float* x    = (const float*)d_in[0];
    const float* w    = (const float*)d_in[1];
    const int*   mask = (const int*)d_in[2];
    float* out = (float*)d_out;

    unsigned short* wpk = (unsigned short*)d_ws;   // 73,728 B

    wpack_kernel<<<72,      64,  0, stream>>>(w, wpk);
    conv_fused  <<<Bn * 98, 256, 0, stream>>>(x, wpk, mask, out);
}